// Round 1
// baseline (3301.951 us; speedup 1.0000x reference)
//
#include <hip/hip_runtime.h>
#include <hip/hip_bf16.h>
#include <math.h>

typedef __attribute__((ext_vector_type(8))) short short8;
typedef __attribute__((ext_vector_type(4))) float f32x4;

// Problem constants
// B=4096, S=64, V=50000, D=300, H=6, E=400, VS=200, DH=50

// ws layout (ushort elements): bf16, transposed (WT[n][k] = W[k][n]), zero padded
#define WQT_OFF 0         // [320][320]
#define WKT_OFF 102400    // [320][320]
#define WVT_OFF 204800    // [320][320]
#define WOT_OFF 307200    // [320][320]
#define WPT_OFF 409600    // [400][320]
#define WAT_OFF 537600    // [208][416]
#define WRT_OFF 624128    // [64][64]
#define WS_TOTAL 628224

__device__ inline unsigned short f2b(float f) {
  unsigned int u = __builtin_bit_cast(unsigned int, f);
  u += 0x7FFFu + ((u >> 16) & 1u);   // RNE round to bf16
  return (unsigned short)(u >> 16);
}
__device__ inline float b2f(unsigned short h) {
  unsigned int u = ((unsigned int)h) << 16;
  return __builtin_bit_cast(float, u);
}

__global__ void prep_weights(const float* __restrict__ Wq, const float* __restrict__ Wk,
                             const float* __restrict__ Wv, const float* __restrict__ Wr,
                             const float* __restrict__ Wo, const float* __restrict__ Wp,
                             const float* __restrict__ Wa, unsigned short* __restrict__ ws) {
  int idx = blockIdx.x * blockDim.x + threadIdx.x;
  if (idx >= WS_TOTAL) return;
  float val = 0.f;
  if (idx < WPT_OFF) {                 // Wq,Wk,Wv,Wo: [300][300] -> [320][320] T
    int m = idx / 102400, local = idx % 102400;
    int n = local / 320, k = local % 320;
    const float* W = (m == 0) ? Wq : (m == 1) ? Wk : (m == 2) ? Wv : Wo;
    if (n < 300 && k < 300) val = W[k * 300 + n];
  } else if (idx < WAT_OFF) {          // Wp: [300][400] -> [400][320] T
    int local = idx - WPT_OFF;
    int n = local / 320, k = local % 320;
    if (k < 300) val = Wp[k * 400 + n];
  } else if (idx < WRT_OFF) {          // Wa: [400][200] -> [208][416] T
    int local = idx - WAT_OFF;
    int n = local / 416, k = local % 416;
    if (n < 200 && k < 400) val = Wa[k * 200 + n];
  } else {                             // Wr: [50][50] -> [64][64] T
    int local = idx - WRT_OFF;
    int n = local / 64, k = local % 64;
    if (n < 50 && k < 50) val = Wr[k * 50 + n];
  }
  ws[idx] = f2b(val);
}

// LDS byte offsets (total 144640 <= 163840)
#define XB_OFF 0        // ushort [64][328]  x, later attn_out
#define RB_OFF 41984    // ushort [64][328]  r
#define QH_OFF 83968    // float  [64][53]   q_head (hb overlays from here in phase E+)
#define KH_OFF 97536    // float  [64][53]
#define VH_OFF 111104   // float  [64][53]
#define UB_OFF 124672   // ushort [64][72]
#define WRT_LDS 133888  // ushort [64][72]
#define HB_OFF 83968    // ushort [64][424]  h (overlays qh/kh/vh/ub, dead by then)
#define MISC_OFF 143360 // float  misc[320]
#define SMEM_BYTES 144640

__global__ __launch_bounds__(256, 1) void doc_encoder(
    const int* __restrict__ tokens, const float* __restrict__ emb,
    const float* __restrict__ wq_attn, const float* __restrict__ wk_attn,
    const float* __restrict__ br_, const float* __restrict__ bo_,
    const float* __restrict__ bp_, const float* __restrict__ ba_,
    const float* __restrict__ va_, const unsigned short* __restrict__ ws,
    float* __restrict__ out) {
  __shared__ alignas(16) unsigned char smem[SMEM_BYTES];
  unsigned short* xb  = (unsigned short*)(smem + XB_OFF);
  unsigned short* rb  = (unsigned short*)(smem + RB_OFF);
  float* qh = (float*)(smem + QH_OFF);
  float* kh = (float*)(smem + KH_OFF);
  float* vh = (float*)(smem + VH_OFF);
  unsigned short* ub  = (unsigned short*)(smem + UB_OFF);
  unsigned short* wrT = (unsigned short*)(smem + WRT_LDS);
  unsigned short* hb  = (unsigned short*)(smem + HB_OFF);
  float* misc = (float*)(smem + MISC_OFF);

  const int b    = blockIdx.x;
  const int tid  = threadIdx.x;
  const int lane = tid & 63;
  const int wv   = tid >> 6;       // wave 0..3 -> M-tile
  const int l15  = lane & 15;
  const int lg   = lane >> 4;      // 0..3
  const int kofs = lg * 8;         // A/B frag: k = 8*(lane>>4) + i (contiguous)
  const int arow = wv * 16 + l15;  // A frag row

  float* alpha  = misc;            // 64 (also beta)
  float* gvec   = misc + 64;       // 64
  float* gkvec  = misc + 128;      // 64
  float* scores = misc + 192;      // 64
  float* wsm    = misc + 256;      // 64

  // ---- Phase 0: gather x = emb[tokens[b]] -> bf16 LDS [64][328], zero-padded ----
  for (int i = tid; i < 64 * 41; i += 256) {
    int s = i / 41, g = i % 41, c = g * 8;
    int tok = tokens[b * 64 + s];
    const float* src = emb + (size_t)tok * 300;
    short8 v;
#pragma unroll
    for (int j = 0; j < 8; ++j) {
      float f = 0.f;
      if (c + j < 300) f = src[c + j];
      v[j] = (short)f2b(f);
    }
    *(short8*)&xb[s * 328 + c] = v;
  }
  for (int i = tid; i < 64 * 28; i += 256) {   // zero rb pad cols 300..327
    int s = i / 28, c = 300 + i % 28;
    rb[s * 328 + c] = 0;
  }
  for (int i = tid; i < 64 * 64; i += 256) {   // stage WrT into LDS (stride 72)
    int n = i >> 6, k = i & 63;
    wrT[n * 72 + k] = ws[WRT_OFF + i];
  }
  __syncthreads();

  const float scale = 0.1414213562373095f;  // 50^-0.5

  for (int h = 0; h < 6; ++h) {
    // ---- Phase B: q,k,v head tiles = x @ W*[:, 50h:50h+50] (MFMA, fp32 out) ----
    {
      const unsigned short* WqT = ws + WQT_OFF;
      const unsigned short* WkT = ws + WKT_OFF;
      const unsigned short* WvT = ws + WVT_OFF;
      for (int t = 0; t < 4; ++t) {
        int bn = h * 50 + t * 16 + l15;  // < 320 always
        f32x4 aq = {0.f, 0.f, 0.f, 0.f}, ak = aq, av = aq;
        const unsigned short* ap  = xb + arow * 328 + kofs;
        const unsigned short* qp  = WqT + (size_t)bn * 320 + kofs;
        const unsigned short* kp  = WkT + (size_t)bn * 320 + kofs;
        const unsigned short* vp  = WvT + (size_t)bn * 320 + kofs;
#pragma unroll
        for (int kt = 0; kt < 10; ++kt) {
          short8 af = *(const short8*)(ap + kt * 32);
          short8 bq = *(const short8*)(qp + kt * 32);
          short8 bk = *(const short8*)(kp + kt * 32);
          short8 bv = *(const short8*)(vp + kt * 32);
          aq = __builtin_amdgcn_mfma_f32_16x16x32_bf16(af, bq, aq, 0, 0, 0);
          ak = __builtin_amdgcn_mfma_f32_16x16x32_bf16(af, bk, ak, 0, 0, 0);
          av = __builtin_amdgcn_mfma_f32_16x16x32_bf16(af, bv, av, 0, 0, 0);
        }
        int col = t * 16 + l15;
        if (col < 50) {
#pragma unroll
          for (int r = 0; r < 4; ++r) {
            int s = wv * 16 + lg * 4 + r;   // verified C/D: row=(lane>>4)*4+r, col=lane&15
            qh[s * 53 + col] = aq[r];
            kh[s * 53 + col] = ak[r];
            vh[s * 53 + col] = av[r];
          }
        }
      }
    }
    __syncthreads();

    // ---- Phase C1: alpha = softmax_s(q . wq_attn * scale) (wave 0, lane=s) ----
    if (wv == 0) {
      float acc = 0.f;
      for (int d = 0; d < 50; ++d) acc += qh[lane * 53 + d] * wq_attn[h * 50 + d];
      acc *= scale;
      float m = acc;
#pragma unroll
      for (int off = 32; off; off >>= 1) m = fmaxf(m, __shfl_xor(m, off));
      float e = __expf(acc - m);
      float ssum = e;
#pragma unroll
      for (int off = 32; off; off >>= 1) ssum += __shfl_xor(ssum, off);
      alpha[lane] = e / ssum;
    }
    __syncthreads();
    // ---- g[d] = sum_s alpha[s] q[s][d] (wave 0, lane=d) ----
    if (wv == 0) {
      int d = lane;
      float acc = 0.f;
      if (d < 50)
        for (int s2 = 0; s2 < 64; ++s2) acc += alpha[s2] * qh[s2 * 53 + d];
      gvec[d] = (d < 50) ? acc : 0.f;
    }
    __syncthreads();
    // ---- beta = softmax_s(sum_d g[d] k[s][d] wk[d] * scale) ----
    if (wv == 0) {
      float acc = 0.f;
      for (int d = 0; d < 50; ++d) acc += gvec[d] * kh[lane * 53 + d] * wk_attn[h * 50 + d];
      acc *= scale;
      float m = acc;
#pragma unroll
      for (int off = 32; off; off >>= 1) m = fmaxf(m, __shfl_xor(m, off));
      float e = __expf(acc - m);
      float ssum = e;
#pragma unroll
      for (int off = 32; off; off >>= 1) ssum += __shfl_xor(ssum, off);
      alpha[lane] = e / ssum;   // beta
    }
    __syncthreads();
    // ---- gk[d] = g[d] * sum_s beta[s] k[s][d] ----
    if (wv == 0) {
      int d = lane;
      float acc = 0.f;
      if (d < 50)
        for (int s2 = 0; s2 < 64; ++s2) acc += alpha[s2] * kh[s2 * 53 + d];
      gkvec[d] = (d < 50) ? gvec[d] * acc : 0.f;
    }
    __syncthreads();
    // ---- u = gk o v -> bf16 [64][72] ----
    for (int i = tid; i < 64 * 64; i += 256) {
      int s = i >> 6, d = i & 63;
      float uvv = (d < 50) ? gkvec[d] * vh[s * 53 + d] : 0.f;
      ub[s * 72 + d] = f2b(uvv);
    }
    __syncthreads();
    // ---- r_h = u @ Wr + br + q -> rb[:, 50h:50h+50] (MFMA) ----
    for (int t = 0; t < 4; ++t) {
      f32x4 acc = {0.f, 0.f, 0.f, 0.f};
#pragma unroll
      for (int kt = 0; kt < 2; ++kt) {
        short8 af = *(const short8*)&ub[arow * 72 + kt * 32 + kofs];
        short8 bf = *(const short8*)&wrT[(t * 16 + l15) * 72 + kt * 32 + kofs];
        acc = __builtin_amdgcn_mfma_f32_16x16x32_bf16(af, bf, acc, 0, 0, 0);
      }
      int j = t * 16 + l15;
      if (j < 50) {
        float brj = br_[j];
#pragma unroll
        for (int r = 0; r < 4; ++r) {
          int s = wv * 16 + lg * 4 + r;
          rb[s * 328 + h * 50 + j] = f2b(acc[r] + brj + qh[s * 53 + j]);
        }
      }
    }
    __syncthreads();
  }

  // ---- Phase D: attn_out = rb @ Wo + bo -> xb (x dead) ----
  {
    const unsigned short* WoT = ws + WOT_OFF;
    for (int t = 0; t < 19; ++t) {
      int bn = t * 16 + l15;   // <= 303
      f32x4 acc = {0.f, 0.f, 0.f, 0.f};
#pragma unroll
      for (int kt = 0; kt < 10; ++kt) {
        short8 af = *(const short8*)&rb[arow * 328 + kt * 32 + kofs];
        short8 bf = *(const short8*)&WoT[(size_t)bn * 320 + kt * 32 + kofs];
        acc = __builtin_amdgcn_mfma_f32_16x16x32_bf16(af, bf, acc, 0, 0, 0);
      }
      float boj = (bn < 300) ? bo_[bn] : 0.f;
#pragma unroll
      for (int r = 0; r < 4; ++r) {
        int s = wv * 16 + lg * 4 + r;
        xb[s * 328 + bn] = f2b(acc[r] + boj);
      }
    }
  }
  __syncthreads();

  // ---- Phase E: h = attn_out @ Wp + bp -> hb [64][424] (overlays q/k/v/u, dead) ----
  {
    for (int i = tid; i < 64 * 24; i += 256) {  // zero pad cols 400..423
      int s = i / 24, c = 400 + i % 24;
      hb[s * 424 + c] = 0;
    }
    const unsigned short* WpT = ws + WPT_OFF;
    for (int t = 0; t < 25; ++t) {
      int bn = t * 16 + l15;   // < 400
      f32x4 acc = {0.f, 0.f, 0.f, 0.f};
#pragma unroll
      for (int kt = 0; kt < 10; ++kt) {
        short8 af = *(const short8*)&xb[arow * 328 + kt * 32 + kofs];
        short8 bf = *(const short8*)&WpT[(size_t)bn * 320 + kt * 32 + kofs];
        acc = __builtin_amdgcn_mfma_f32_16x16x32_bf16(af, bf, acc, 0, 0, 0);
      }
      float bpj = bp_[bn];
#pragma unroll
      for (int r = 0; r < 4; ++r) {
        int s = wv * 16 + lg * 4 + r;
        hb[s * 424 + bn] = f2b(acc[r] + bpj);
      }
    }
  }
  __syncthreads();

  // ---- Phase F: scores = tanh(h @ Wa + ba) @ va ; softmax_s ; pooled ----
  {
    const unsigned short* WaT = ws + WAT_OFF;
    float sp[4] = {0.f, 0.f, 0.f, 0.f};
    for (int t = 0; t < 13; ++t) {
      int bn = t * 16 + l15;   // < 208
      f32x4 acc = {0.f, 0.f, 0.f, 0.f};
#pragma unroll
      for (int kt = 0; kt < 13; ++kt) {
        short8 af = *(const short8*)&hb[arow * 424 + kt * 32 + kofs];
        short8 bf = *(const short8*)&WaT[(size_t)bn * 416 + kt * 32 + kofs];
        acc = __builtin_amdgcn_mfma_f32_16x16x32_bf16(af, bf, acc, 0, 0, 0);
      }
      if (bn < 200) {
        float vaj = va_[bn], baj = ba_[bn];
#pragma unroll
        for (int r = 0; r < 4; ++r) sp[r] += tanhf(acc[r] + baj) * vaj;
      }
    }
#pragma unroll
    for (int off = 1; off < 16; off <<= 1) {
#pragma unroll
      for (int r = 0; r < 4; ++r) sp[r] += __shfl_xor(sp[r], off);
    }
    if (l15 == 0) {
#pragma unroll
      for (int r = 0; r < 4; ++r) scores[wv * 16 + lg * 4 + r] = sp[r];
    }
  }
  __syncthreads();
  if (wv == 0) {
    float x = scores[lane];
    float m = x;
#pragma unroll
    for (int off = 32; off; off >>= 1) m = fmaxf(m, __shfl_xor(m, off));
    float e = __expf(x - m);
    float ssum = e;
#pragma unroll
    for (int off = 32; off; off >>= 1) ssum += __shfl_xor(ssum, off);
    wsm[lane] = e / ssum;
  }
  __syncthreads();
  for (int e0 = tid; e0 < 400; e0 += 256) {
    float acc = 0.f;
    for (int s2 = 0; s2 < 64; ++s2) acc += wsm[s2] * b2f(hb[s2 * 424 + e0]);
    out[(size_t)b * 400 + e0] = acc;
  }
}

extern "C" void kernel_launch(void* const* d_in, const int* in_sizes, int n_in,
                              void* d_out, int out_size, void* d_ws, size_t ws_size,
                              hipStream_t stream) {
  (void)in_sizes; (void)n_in; (void)out_size; (void)ws_size;
  const int*   tokens  = (const int*)d_in[0];
  const float* emb     = (const float*)d_in[1];
  const float* Wq      = (const float*)d_in[2];
  const float* Wk      = (const float*)d_in[3];
  const float* Wv      = (const float*)d_in[4];
  const float* wq_attn = (const float*)d_in[5];
  const float* wk_attn = (const float*)d_in[6];
  const float* Wr      = (const float*)d_in[7];
  const float* br      = (const float*)d_in[8];
  const float* Wo      = (const float*)d_in[9];
  const float* bo      = (const float*)d_in[10];
  const float* Wp      = (const float*)d_in[11];
  const float* bp      = (const float*)d_in[12];
  const float* Wa      = (const float*)d_in[13];
  const float* ba      = (const float*)d_in[14];
  const float* va      = (const float*)d_in[15];
  unsigned short* wsb  = (unsigned short*)d_ws;
  float* out           = (float*)d_out;

  prep_weights<<<(WS_TOTAL + 255) / 256, 256, 0, stream>>>(Wq, Wk, Wv, Wr, Wo, Wp, Wa, wsb);
  doc_encoder<<<4096, 256, 0, stream>>>(tokens, emb, wq_attn, wk_attn, br, bo, bp, ba, va,
                                        wsb, out);
}

// Round 2
// 1160.047 us; speedup vs baseline: 2.8464x; 2.8464x over previous
//
#include <hip/hip_runtime.h>
#include <hip/hip_bf16.h>
#include <math.h>

typedef __attribute__((ext_vector_type(8))) short short8;
typedef __attribute__((ext_vector_type(4))) float f32x4;

// B=4096, S=64, V=50000, D=300, H=6, E=400, VS=200, DH=50

// ws layout (ushort): fragment-packed 16x32 MFMA B-tiles, 512 elems each,
// element (lane,i) = W[k][n] with n = tn*16+(lane&15), k = kt*32+(lane>>4)*8+i
#define QF0 0        // [6 h][4 tn][10 kt][512]  (per-head Q, col 50 = cq_h)
#define KF0 122880   // [6][4][10][512]
#define VF0 245760   // [6][4][10][512]
#define OF0 368640   // [19 tn][10 kt][512]
#define PF0 465920   // [25 tn][10 kt][512]
#define AF0 593920   // [13 tn][13 kt][512]
#define WR0 680448   // [64][64] plain transposed
#define WS_TOTAL 684544

__device__ __forceinline__ unsigned short f2b(float f) {
  unsigned int u = __builtin_bit_cast(unsigned int, f);
  u += 0x7FFFu + ((u >> 16) & 1u);
  return (unsigned short)(u >> 16);
}
__device__ __forceinline__ float b2f(unsigned short h) {
  unsigned int u = ((unsigned int)h) << 16;
  return __builtin_bit_cast(float, u);
}

__global__ void prep_weights(const float* __restrict__ Wq, const float* __restrict__ Wk,
                             const float* __restrict__ Wv, const float* __restrict__ Wr,
                             const float* __restrict__ Wo, const float* __restrict__ Wp,
                             const float* __restrict__ Wa, const float* __restrict__ wq_attn,
                             unsigned short* __restrict__ ws) {
  int idx = blockIdx.x * blockDim.x + threadIdx.x;
  if (idx >= WS_TOTAL) return;
  float val = 0.f;
  if (idx < OF0) {                         // per-head Q/K/V
    int m = idx / 122880;
    int r = idx % 122880;
    int h = r / 20480; r %= 20480;
    int tn = r / 5120; r %= 5120;
    int kt = r / 512;  r %= 512;
    int lane = r >> 3, i = r & 7;
    int nl = tn * 16 + (lane & 15);
    int k  = kt * 32 + (lane >> 4) * 8 + i;
    if (k < 300) {
      if (nl < 50) {
        const float* W = (m == 0) ? Wq : (m == 1) ? Wk : Wv;
        val = W[k * 300 + h * 50 + nl];
      } else if (nl == 50 && m == 0) {     // augmented column: cq_h[k]
        float s = 0.f;
        for (int d = 0; d < 50; ++d) s += Wq[k * 300 + h * 50 + d] * wq_attn[h * 50 + d];
        val = s;
      }
    }
  } else if (idx < PF0) {                  // Wo
    int r = idx - OF0;
    int tn = r / 5120; r %= 5120;
    int kt = r / 512;  r %= 512;
    int lane = r >> 3, i = r & 7;
    int n = tn * 16 + (lane & 15);
    int k = kt * 32 + (lane >> 4) * 8 + i;
    if (n < 300 && k < 300) val = Wo[k * 300 + n];
  } else if (idx < AF0) {                  // Wp
    int r = idx - PF0;
    int tn = r / 5120; r %= 5120;
    int kt = r / 512;  r %= 512;
    int lane = r >> 3, i = r & 7;
    int n = tn * 16 + (lane & 15);
    int k = kt * 32 + (lane >> 4) * 8 + i;
    if (k < 300) val = Wp[k * 400 + n];
  } else if (idx < WR0) {                  // Wa
    int r = idx - AF0;
    int tn = r / 6656; r %= 6656;
    int kt = r / 512;  r %= 512;
    int lane = r >> 3, i = r & 7;
    int n = tn * 16 + (lane & 15);
    int k = kt * 32 + (lane >> 4) * 8 + i;
    if (n < 200 && k < 400) val = Wa[k * 200 + n];
  } else {                                 // Wr transposed [64][64]
    int r = idx - WR0;
    int n = r >> 6, k = r & 63;
    if (n < 50 && k < 50) val = Wr[k * 50 + n];
  }
  ws[idx] = f2b(val);
}

// LDS byte offsets (total 142592 <= 163840)
#define XB_OFF 0        // ushort [64][328]  x, later attn_out
#define RB_OFF 41984    // ushort [64][328]  r
#define QH_OFF 83968    // float  [64][53]
#define KH_OFF 97536    // float  [64][53]
#define VH_OFF 111104   // ushort [64][72]
#define WRT_OFF_L 120320 // ushort [64][72]
#define HB_OFF 83968    // ushort [64][424]  overlays qh/kh/vh/wrT after heads
#define MISC_OFF 138240 // float [1088]
#define SMEM_BYTES 142592

template <int KT>
__device__ __forceinline__ void loadBT(short8* b, const unsigned short* p) {
#pragma unroll
  for (int kt = 0; kt < KT; ++kt) b[kt] = *(const short8*)(p + kt * 512);
}
template <int KT>
__device__ __forceinline__ f32x4 chainT(const short8* a, const short8* b) {
  f32x4 acc = {0.f, 0.f, 0.f, 0.f};
#pragma unroll
  for (int kt = 0; kt < KT; ++kt)
    acc = __builtin_amdgcn_mfma_f32_16x16x32_bf16(a[kt], b[kt], acc, 0, 0, 0);
  return acc;
}

template <int KT, typename Epi>
__device__ __forceinline__ void gemm_tiles(const unsigned short* wbase, const short8* a,
                                           int tb, int te, int lane, Epi epi) {
  short8 b0[KT], b1[KT];
  int t = tb;
  loadBT<KT>(b0, wbase + (size_t)t * (KT * 512) + lane * 8);
  while (true) {
    if (t + 1 < te) loadBT<KT>(b1, wbase + (size_t)(t + 1) * (KT * 512) + lane * 8);
    { f32x4 acc = chainT<KT>(a, b0); epi(t, acc); }
    ++t; if (t >= te) break;
    if (t + 1 < te) loadBT<KT>(b0, wbase + (size_t)(t + 1) * (KT * 512) + lane * 8);
    { f32x4 acc = chainT<KT>(a, b1); epi(t, acc); }
    ++t; if (t >= te) break;
  }
}

__global__ __launch_bounds__(512, 1) void doc_encoder(
    const int* __restrict__ tokens, const float* __restrict__ emb,
    const float* __restrict__ wk_attn,
    const float* __restrict__ br_, const float* __restrict__ bo_,
    const float* __restrict__ bp_, const float* __restrict__ ba_,
    const float* __restrict__ va_, const unsigned short* __restrict__ ws,
    float* __restrict__ out) {
  __shared__ alignas(16) unsigned char smem[SMEM_BYTES];
  unsigned short* xb  = (unsigned short*)(smem + XB_OFF);
  unsigned short* rb  = (unsigned short*)(smem + RB_OFF);
  float* qh = (float*)(smem + QH_OFF);
  float* kh = (float*)(smem + KH_OFF);
  unsigned short* vh  = (unsigned short*)(smem + VH_OFF);
  unsigned short* wrT = (unsigned short*)(smem + WRT_OFF_L);
  unsigned short* hb  = (unsigned short*)(smem + HB_OFF);
  float* misc = (float*)(smem + MISC_OFF);

  float* qw_   = misc;        // 64
  float* alpha = misc + 64;   // 64
  float* g_    = misc + 128;  // 64
  float* gw_   = misc + 192;  // 64
  float* beta  = misc + 256;  // 64
  float* gk_   = misc + 320;  // 64
  float* part  = misc + 384;  // [8][64]
  float* scp   = misc + 896;  // [2][64]
  float* wsm   = misc + 1024; // 64

  const int b    = blockIdx.x;
  const int tid  = threadIdx.x;
  const int lane = tid & 63;
  const int wv   = tid >> 6;       // 0..7
  const int wm   = wv & 3;         // M-tile
  const int wn   = wv >> 2;        // N-half
  const int l15  = lane & 15;
  const int lg   = lane >> 4;
  const int kofs = lg * 8;
  const int arow = wm * 16 + l15;
  const int crow0 = wm * 16 + lg * 4;

  // ---- gather x = emb[tokens[b]] -> bf16 [64][328] (pad zeros) ----
  for (int i = tid; i < 64 * 41; i += 512) {
    int s = i / 41, gidx = i % 41, c = gidx * 8;
    int tok = tokens[b * 64 + s];
    const float* src = emb + (size_t)tok * 300;
    short8 v;
#pragma unroll
    for (int j = 0; j < 8; ++j) {
      float f = (c + j < 300) ? src[c + j] : 0.f;
      v[j] = (short)f2b(f);
    }
    *(short8*)&xb[s * 328 + c] = v;
  }
  for (int i = tid; i < 4096; i += 512) {   // stage WrT (stride 72)
    int n = i >> 6, k = i & 63;
    wrT[n * 72 + k] = ws[WR0 + i];
  }
  __syncthreads();

  // A-fragments of x: constant across all 6 heads' QKV GEMMs
  short8 ax[10];
#pragma unroll
  for (int kt = 0; kt < 10; ++kt)
    ax[kt] = *(const short8*)&xb[arow * 328 + kt * 32 + kofs];

  const float scale = 0.1414213562373095f;  // 50^-0.5

  for (int h = 0; h < 6; ++h) {
    // ---- Phase B: q,k,v head tiles via pipelined fragment loads ----
    {
      const int t0 = wn * 2, t1 = wn * 2 + 1;
      const unsigned short* q0p = ws + QF0 + (size_t)(h * 4 + t0) * 5120 + lane * 8;
      const unsigned short* k0p = ws + KF0 + (size_t)(h * 4 + t0) * 5120 + lane * 8;
      const unsigned short* v0p = ws + VF0 + (size_t)(h * 4 + t0) * 5120 + lane * 8;
      const unsigned short* q1p = ws + QF0 + (size_t)(h * 4 + t1) * 5120 + lane * 8;
      const unsigned short* k1p = ws + KF0 + (size_t)(h * 4 + t1) * 5120 + lane * 8;
      const unsigned short* v1p = ws + VF0 + (size_t)(h * 4 + t1) * 5120 + lane * 8;

      auto epiQ = [&](int t, f32x4 acc) {
        int j = t * 16 + l15;
        if (j < 50) {
#pragma unroll
          for (int r = 0; r < 4; ++r) qh[(crow0 + r) * 53 + j] = acc[r];
        } else if (j == 50) {
#pragma unroll
          for (int r = 0; r < 4; ++r) qw_[crow0 + r] = acc[r] * scale;
        }
      };
      auto epiK = [&](int t, f32x4 acc) {
        int j = t * 16 + l15;
        if (j < 50) {
#pragma unroll
          for (int r = 0; r < 4; ++r) kh[(crow0 + r) * 53 + j] = acc[r];
        }
      };
      auto epiV = [&](int t, f32x4 acc) {
        int j = t * 16 + l15;
#pragma unroll
        for (int r = 0; r < 4; ++r)
          vh[(crow0 + r) * 72 + j] = (j < 50) ? f2b(acc[r]) : (unsigned short)0;
      };

      short8 bx[10], by[10], bz[10];
      loadBT<10>(bx, q0p);
      loadBT<10>(by, k0p);
      loadBT<10>(bz, v0p);
      f32x4 acc;
      acc = chainT<10>(ax, bx); loadBT<10>(bx, q1p); epiQ(t0, acc);
      acc = chainT<10>(ax, by); loadBT<10>(by, k1p); epiK(t0, acc);
      acc = chainT<10>(ax, bz); loadBT<10>(bz, v1p); epiV(t0, acc);
      acc = chainT<10>(ax, bx); epiQ(t1, acc);
      acc = chainT<10>(ax, by); epiK(t1, acc);
      acc = chainT<10>(ax, bz); epiV(t1, acc);
    }
    __syncthreads();

    // ---- Stage C (parallelized) ----
    if (wv == 0) {   // alpha = softmax(qw)
      float x = qw_[lane];
      float m = x;
#pragma unroll
      for (int off = 32; off; off >>= 1) m = fmaxf(m, __shfl_xor(m, off));
      float e = __expf(x - m);
      float ss = e;
#pragma unroll
      for (int off = 32; off; off >>= 1) ss += __shfl_xor(ss, off);
      alpha[lane] = e / ss;
    }
    __syncthreads();
    {  // g partials: wave wv covers s in [8wv, 8wv+8)
      float p = 0.f;
      int s0 = wv * 8;
      if (lane < 50) {
#pragma unroll
        for (int s = 0; s < 8; ++s) p += alpha[s0 + s] * qh[(s0 + s) * 53 + lane];
      }
      part[wv * 64 + lane] = p;
    }
    __syncthreads();
    if (wv == 0) {  // g, gw = g*wk_attn
      float s_ = 0.f;
      if (lane < 50) {
#pragma unroll
        for (int w = 0; w < 8; ++w) s_ += part[w * 64 + lane];
      }
      g_[lane] = s_;
      gw_[lane] = (lane < 50) ? s_ * wk_attn[h * 50 + lane] : 0.f;
    }
    __syncthreads();
    {  // beta-logit partials: wave wv covers d-slice
      int d0 = wv * 7;
      int d1 = d0 + 7; if (d1 > 50) d1 = 50;
      float p = 0.f;
      for (int d = d0; d < d1; ++d) p += gw_[d] * kh[lane * 53 + d];
      part[wv * 64 + lane] = p;
    }
    __syncthreads();
    if (wv == 0) {  // beta = softmax
      float bl = 0.f;
#pragma unroll
      for (int w = 0; w < 8; ++w) bl += part[w * 64 + lane];
      bl *= scale;
      float m = bl;
#pragma unroll
      for (int off = 32; off; off >>= 1) m = fmaxf(m, __shfl_xor(m, off));
      float e = __expf(bl - m);
      float ss = e;
#pragma unroll
      for (int off = 32; off; off >>= 1) ss += __shfl_xor(ss, off);
      beta[lane] = e / ss;
    }
    __syncthreads();
    {  // gk partials
      float p = 0.f;
      int s0 = wv * 8;
      if (lane < 50) {
#pragma unroll
        for (int s = 0; s < 8; ++s) p += beta[s0 + s] * kh[(s0 + s) * 53 + lane];
      }
      part[wv * 64 + lane] = p;
    }
    __syncthreads();
    if (wv == 0) {
      float s_ = 0.f;
      if (lane < 50) {
#pragma unroll
        for (int w = 0; w < 8; ++w) s_ += part[w * 64 + lane];
      }
      gk_[lane] = (lane < 50) ? g_[lane] * s_ : 0.f;
    }
    __syncthreads();

    // ---- r = (gk o v) @ Wr + br + q -> rb[:, 50h .. 50h+50) ----
    {
      short8 au[2];
#pragma unroll
      for (int kt = 0; kt < 2; ++kt) {
        short8 vf = *(const short8*)&vh[arow * 72 + kt * 32 + kofs];
        short8 uf;
#pragma unroll
        for (int i2 = 0; i2 < 8; ++i2) {
          float gkv = gk_[kt * 32 + kofs + i2];
          uf[i2] = (short)f2b(gkv * b2f((unsigned short)vf[i2]));
        }
        au[kt] = uf;
      }
#pragma unroll
      for (int tt = 0; tt < 2; ++tt) {
        int t = wn * 2 + tt;
        f32x4 acc2 = {0.f, 0.f, 0.f, 0.f};
#pragma unroll
        for (int kt = 0; kt < 2; ++kt) {
          short8 bf = *(const short8*)&wrT[(t * 16 + l15) * 72 + kt * 32 + kofs];
          acc2 = __builtin_amdgcn_mfma_f32_16x16x32_bf16(au[kt], bf, acc2, 0, 0, 0);
        }
        int j = t * 16 + l15;
        if (j < 50) {
          float brj = br_[j];
#pragma unroll
          for (int r = 0; r < 4; ++r)
            rb[(crow0 + r) * 328 + h * 50 + j] =
                f2b(acc2[r] + brj + qh[(crow0 + r) * 53 + j]);
        }
      }
    }
    __syncthreads();
  }

  // ---- Phase D: attn_out = rb @ Wo + bo -> xb ----
  {
    short8 a2[10];
#pragma unroll
    for (int kt = 0; kt < 10; ++kt)
      a2[kt] = *(const short8*)&rb[arow * 328 + kt * 32 + kofs];
    int tb = wn ? 10 : 0, te = wn ? 19 : 10;
    gemm_tiles<10>(ws + OF0, a2, tb, te, lane, [&](int t, f32x4 acc) {
      int n = t * 16 + l15;
      float boj = (n < 300) ? bo_[n] : 0.f;
#pragma unroll
      for (int r = 0; r < 4; ++r) xb[(crow0 + r) * 328 + n] = f2b(acc[r] + boj);
    });
  }
  __syncthreads();

  // ---- Phase E: h = attn_out @ Wp + bp -> hb [64][424] ----
  {
    for (int i = tid; i < 64 * 16; i += 512)   // zero pad cols 400..415
      hb[(i >> 4) * 424 + 400 + (i & 15)] = 0;
    short8 a2[10];
#pragma unroll
    for (int kt = 0; kt < 10; ++kt)
      a2[kt] = *(const short8*)&xb[arow * 328 + kt * 32 + kofs];
    int tb = wn ? 13 : 0, te = wn ? 25 : 13;
    gemm_tiles<10>(ws + PF0, a2, tb, te, lane, [&](int t, f32x4 acc) {
      int n = t * 16 + l15;
      float bpj = bp_[n];
#pragma unroll
      for (int r = 0; r < 4; ++r) hb[(crow0 + r) * 424 + n] = f2b(acc[r] + bpj);
    });
  }
  __syncthreads();

  // ---- Phase F: scores = tanh(h @ Wa + ba) @ va ----
  {
    short8 a3[13];
#pragma unroll
    for (int kt = 0; kt < 13; ++kt)
      a3[kt] = *(const short8*)&hb[arow * 424 + kt * 32 + kofs];
    float sp[4] = {0.f, 0.f, 0.f, 0.f};
    int tb = wn ? 7 : 0, te = wn ? 13 : 7;
    gemm_tiles<13>(ws + AF0, a3, tb, te, lane, [&](int t, f32x4 acc) {
      int n = t * 16 + l15;
      if (n < 200) {
        float ban = ba_[n], van = va_[n];
#pragma unroll
        for (int r = 0; r < 4; ++r) sp[r] += tanhf(acc[r] + ban) * van;
      }
    });
#pragma unroll
    for (int off = 1; off < 16; off <<= 1) {
#pragma unroll
      for (int r = 0; r < 4; ++r) sp[r] += __shfl_xor(sp[r], off);
    }
    if (l15 == 0) {
#pragma unroll
      for (int r = 0; r < 4; ++r) scp[wn * 64 + crow0 + r] = sp[r];
    }
  }
  __syncthreads();
  if (wv == 0) {
    float x = scp[lane] + scp[64 + lane];
    float m = x;
#pragma unroll
    for (int off = 32; off; off >>= 1) m = fmaxf(m, __shfl_xor(m, off));
    float e = __expf(x - m);
    float ss = e;
#pragma unroll
    for (int off = 32; off; off >>= 1) ss += __shfl_xor(ss, off);
    wsm[lane] = e / ss;
  }
  __syncthreads();

  // ---- pooled[e] = sum_s wsm[s] * h[s][e] ----
  if (tid < 400) {
    float a0 = 0.f, a1 = 0.f, a2 = 0.f, a3 = 0.f;
    for (int s = 0; s < 64; s += 4) {
      a0 += wsm[s]     * b2f(hb[s * 424 + tid]);
      a1 += wsm[s + 1] * b2f(hb[(s + 1) * 424 + tid]);
      a2 += wsm[s + 2] * b2f(hb[(s + 2) * 424 + tid]);
      a3 += wsm[s + 3] * b2f(hb[(s + 3) * 424 + tid]);
    }
    out[(size_t)b * 400 + tid] = (a0 + a1) + (a2 + a3);
  }
}

extern "C" void kernel_launch(void* const* d_in, const int* in_sizes, int n_in,
                              void* d_out, int out_size, void* d_ws, size_t ws_size,
                              hipStream_t stream) {
  (void)in_sizes; (void)n_in; (void)out_size; (void)ws_size;
  const int*   tokens  = (const int*)d_in[0];
  const float* emb     = (const float*)d_in[1];
  const float* Wq      = (const float*)d_in[2];
  const float* Wk      = (const float*)d_in[3];
  const float* Wv      = (const float*)d_in[4];
  const float* wq_attn = (const float*)d_in[5];
  const float* wk_attn = (const float*)d_in[6];
  const float* Wr      = (const float*)d_in[7];
  const float* br      = (const float*)d_in[8];
  const float* Wo      = (const float*)d_in[9];
  const float* bo      = (const float*)d_in[10];
  const float* Wp      = (const float*)d_in[11];
  const float* bp      = (const float*)d_in[12];
  const float* Wa      = (const float*)d_in[13];
  const float* ba      = (const float*)d_in[14];
  const float* va      = (const float*)d_in[15];
  unsigned short* wsb  = (unsigned short*)d_ws;
  float* out           = (float*)d_out;

  prep_weights<<<(WS_TOTAL + 255) / 256, 256, 0, stream>>>(Wq, Wk, Wv, Wr, Wo, Wp, Wa,
                                                           wq_attn, wsb);
  doc_encoder<<<4096, 512, 0, stream>>>(tokens, emb, wk_attn, br, bo, bp, ba, va, wsb, out);
}

// Round 3
// 910.949 us; speedup vs baseline: 3.6247x; 1.2734x over previous
//
#include <hip/hip_runtime.h>
#include <hip/hip_bf16.h>
#include <math.h>

typedef __attribute__((ext_vector_type(8))) short short8;
typedef __attribute__((ext_vector_type(4))) float f32x4;

// B=4096, S=64, V=50000, D=300, H=6, E=400, VS=200, DH=50

// ws layout (ushort elems): MFMA B-frag tiles, 512 elems each:
// elem(lane,i) = W[k][n], n = tn*16+(lane&15), k = kt*32+(lane>>4)*8+i
#define QF 0        // [20 tn][10 kt][512]  Wq + aug cols n=300..305 (cq_h)
#define KF 102400   // [19][10][512]  Wk
#define VF 199680   // [19][10][512]  Wv
#define OF 296960   // [19][10][512]  Wo
#define RF 394240   // [19][10][512]  Wro = Wr @ Wo (per-head block product)
#define PFW 491520  // [25][10][512]  Wp
#define AFW 619520  // [13][13][512]  Wa
#define BOBF 706048 // float[304] at byte 2*BOBF: fused attn bias bo + br@Wo
#define PREP_TOTAL (706048 + 304)

__device__ __forceinline__ unsigned short f2b(float f) {
  unsigned int u = __builtin_bit_cast(unsigned int, f);
  u += 0x7FFFu + ((u >> 16) & 1u);
  return (unsigned short)(u >> 16);
}
__device__ __forceinline__ float b2f(unsigned short h) {
  unsigned int u = ((unsigned int)h) << 16;
  return __builtin_bit_cast(float, u);
}

__global__ void prep_weights(const float* __restrict__ Wq, const float* __restrict__ Wk,
                             const float* __restrict__ Wv, const float* __restrict__ Wr,
                             const float* __restrict__ Wo, const float* __restrict__ Wp,
                             const float* __restrict__ Wa, const float* __restrict__ wq_attn,
                             const float* __restrict__ br, const float* __restrict__ bo,
                             unsigned short* __restrict__ ws) {
  int idx = blockIdx.x * blockDim.x + threadIdx.x;
  if (idx >= PREP_TOTAL) return;
  if (idx >= BOBF) {                      // fused attn-out bias (fp32)
    int n = idx - BOBF;                   // 0..303
    float s = 0.f;
    if (n < 300) {
      s = bo[n];
      for (int m = 0; m < 300; ++m) s += br[m % 50] * Wo[m * 300 + n];
    }
    ((float*)(ws))[BOBF / 2 + n] = s;
    return;
  }
  float val = 0.f;
  if (idx < KF) {                         // Q' = [Wq | cq_h]
    int tn = idx / 5120, r = idx % 5120;
    int kt = r / 512; r &= 511;
    int lane = r >> 3, i = r & 7;
    int n = tn * 16 + (lane & 15), k = kt * 32 + (lane >> 4) * 8 + i;
    if (k < 300) {
      if (n < 300) val = Wq[k * 300 + n];
      else if (n < 306) {
        int h = n - 300;
        float s = 0.f;
        for (int d = 0; d < 50; ++d) s += Wq[k * 300 + 50 * h + d] * wq_attn[h * 50 + d];
        val = s;
      }
    }
  } else if (idx < RF) {                  // Wk / Wv / Wo (plain 300x300)
    int m = (idx - KF) / 97280;
    int local = (idx - KF) % 97280;
    int tn = local / 5120, r = local % 5120;
    int kt = r / 512; r &= 511;
    int lane = r >> 3, i = r & 7;
    int n = tn * 16 + (lane & 15), k = kt * 32 + (lane >> 4) * 8 + i;
    if (n < 300 && k < 300) {
      const float* W = (m == 0) ? Wk : (m == 1) ? Wv : Wo;
      val = W[k * 300 + n];
    }
  } else if (idx < PFW) {                 // Wro[k][n] = sum_j Wr[k%50][j]*Wo[50*(k/50)+j][n]
    int local = idx - RF;
    int tn = local / 5120, r = local % 5120;
    int kt = r / 512; r &= 511;
    int lane = r >> 3, i = r & 7;
    int n = tn * 16 + (lane & 15), k = kt * 32 + (lane >> 4) * 8 + i;
    if (n < 300 && k < 300) {
      int h = k / 50, i2 = k % 50;
      float s = 0.f;
      for (int j = 0; j < 50; ++j) s += Wr[i2 * 50 + j] * Wo[(50 * h + j) * 300 + n];
      val = s;
    }
  } else if (idx < AFW) {                 // Wp [300][400]
    int local = idx - PFW;
    int tn = local / 5120, r = local % 5120;
    int kt = r / 512; r &= 511;
    int lane = r >> 3, i = r & 7;
    int n = tn * 16 + (lane & 15), k = kt * 32 + (lane >> 4) * 8 + i;
    if (k < 300) val = Wp[k * 400 + n];
  } else {                                // Wa [400][200], 13 kt
    int local = idx - AFW;
    int tn = local / 6656, r = local % 6656;
    int kt = r / 512; r &= 511;
    int lane = r >> 3, i = r & 7;
    int n = tn * 16 + (lane & 15), k = kt * 32 + (lane >> 4) * 8 + i;
    if (n < 200 && k < 400) val = Wa[k * 200 + n];
  }
  ws[idx] = f2b(val);
}

// LDS layout (bytes), total 120576
#define KB_OFF 0        // ushort [64][306]  K, then attn_out
#define QB_OFF 39168    // ushort [64][302]  q (bf16)
#define VB_OFF 77824    // ushort [64][302]  v (bf16)
#define HB_OFF 39168    // ushort [64][402]  h (overlays qb+vb after attn)
#define MISC_OFF 116480 // float[1024]: aM[384] gkf[320] scp[256] wsm[64]
#define SMEM_BYTES 120576

template <int KT>
__device__ __forceinline__ void loadBT(short8* b, const unsigned short* p) {
#pragma unroll
  for (int kt = 0; kt < KT; ++kt) b[kt] = *(const short8*)(p + kt * 512);
}

template <int KT>
__device__ __forceinline__ void chain2(const short8* a0, const short8* a1, const short8* bf,
                                       f32x4& c0, f32x4& c1) {
  c0 = {0.f, 0.f, 0.f, 0.f};
  c1 = {0.f, 0.f, 0.f, 0.f};
#pragma unroll
  for (int k = 0; k < KT; ++k) {
    c0 = __builtin_amdgcn_mfma_f32_16x16x32_bf16(a0[k], bf[k], c0, 0, 0, 0);
    c1 = __builtin_amdgcn_mfma_f32_16x16x32_bf16(a1[k], bf[k], c1, 0, 0, 0);
  }
}

// 2 M-tiles per wave, 4-way N split (tn = w4, w4+4, ...), 2-deep B prefetch.
template <int KT, typename Epi>
__device__ __forceinline__ void gemm2(const unsigned short* wbase, const short8* a0,
                                      const short8* a1, int w4, int nt, int lane, Epi epi) {
  short8 b0[KT], b1[KT];
  int t = w4;
  loadBT<KT>(b0, wbase + (size_t)t * (KT * 512) + lane * 8);
  f32x4 c0, c1;
  while (true) {
    if (t + 4 < nt) loadBT<KT>(b1, wbase + (size_t)(t + 4) * (KT * 512) + lane * 8);
    chain2<KT>(a0, a1, b0, c0, c1);
    epi(t, c0, c1);
    t += 4; if (t >= nt) break;
    if (t + 4 < nt) loadBT<KT>(b0, wbase + (size_t)(t + 4) * (KT * 512) + lane * 8);
    chain2<KT>(a0, a1, b1, c0, c1);
    epi(t, c0, c1);
    t += 4; if (t >= nt) break;
  }
}

__global__ __launch_bounds__(512, 1) void doc_encoder(
    const int* __restrict__ tokens, const float* __restrict__ emb,
    const float* __restrict__ wk_attn, const float* __restrict__ bp_,
    const float* __restrict__ ba_, const float* __restrict__ va_,
    const unsigned short* __restrict__ ws, float* __restrict__ out) {
  __shared__ alignas(16) unsigned char smem[SMEM_BYTES];
  unsigned short* kb = (unsigned short*)(smem + KB_OFF);
  unsigned short* qb = (unsigned short*)(smem + QB_OFF);
  unsigned short* vb = (unsigned short*)(smem + VB_OFF);
  unsigned short* hb = (unsigned short*)(smem + HB_OFF);
  float* miscf = (float*)(smem + MISC_OFF);
  float* gkf = miscf + 384;   // [320]
  float* scp = miscf + 704;   // [4][64]
  float* wsm = miscf + 960;   // [64]

  const int b = blockIdx.x;
  const int tid = threadIdx.x;
  const int lane = tid & 63;
  const int wv = tid >> 6;       // 0..7
  const int wm2 = wv & 1;        // M half (rows wm2*32 .. +32)
  const int w4 = wv >> 1;        // 4-way N split
  const int l15 = lane & 15;
  const int lg = lane >> 4;
  const int kofs = lg * 8;
  const int arow0 = wm2 * 32 + l15;
  const int arow1 = arow0 + 16;
  const int cr0 = wm2 * 32 + lg * 4;   // C rows tile0; tile1 = +16
  const float* bobf = (const float*)(ws + BOBF);

  // ---- zero pads (visible after first barrier) ----
  for (int i = tid; i < 128; i += 512) qb[(i >> 1) * 302 + 300 + (i & 1)] = 0;
  for (int i = tid; i < 384; i += 512) kb[(i / 6) * 306 + 300 + (i % 6)] = 0;
  if (tid < 20) gkf[300 + tid] = 0.f;

  // ---- gather x rows straight into A-fragments (registers) ----
  short8 ax0[10], ax1[10];
  {
    int tok0 = tokens[b * 64 + arow0];
    int tok1 = tokens[b * 64 + arow1];
    const float* rp0 = emb + (size_t)tok0 * 300;
    const float* rp1 = emb + (size_t)tok1 * 300;
#pragma unroll
    for (int kt = 0; kt < 9; ++kt) {
      f32x4 u0 = *(const f32x4*)(rp0 + kt * 32 + kofs);
      f32x4 u1 = *(const f32x4*)(rp0 + kt * 32 + kofs + 4);
      f32x4 v0 = *(const f32x4*)(rp1 + kt * 32 + kofs);
      f32x4 v1 = *(const f32x4*)(rp1 + kt * 32 + kofs + 4);
      short8 t0, t1;
#pragma unroll
      for (int j = 0; j < 4; ++j) {
        t0[j] = (short)f2b(u0[j]); t0[4 + j] = (short)f2b(u1[j]);
        t1[j] = (short)f2b(v0[j]); t1[4 + j] = (short)f2b(v1[j]);
      }
      ax0[kt] = t0; ax1[kt] = t1;
    }
    short8 t0, t1;
#pragma unroll
    for (int j = 0; j < 8; ++j) {
      int c = 288 + kofs + j;
      t0[j] = (c < 300) ? (short)f2b(rp0[c]) : (short)0;
      t1[j] = (c < 300) ? (short)f2b(rp1[c]) : (short)0;
    }
    ax0[9] = t0; ax1[9] = t1;
  }

  const float scale = 0.1414213562373095f;  // 50^-0.5

  // ---- Phase B: Q'(20) K(19) V(19) = 58 tile-jobs, parity w4 ----
  {
    auto jobPtr = [&](int j) -> const unsigned short* {
      size_t off;
      if (j < 20) off = QF + (size_t)j * 5120;
      else if (j < 39) off = KF + (size_t)(j - 20) * 5120;
      else off = VF + (size_t)(j - 39) * 5120;
      return ws + off + lane * 8;
    };
    auto bEpi = [&](int j, f32x4 c0, f32x4 c1) {
      if (j < 20) {
        int n = j * 16 + l15;
        if (n < 300) {
#pragma unroll
          for (int r = 0; r < 4; ++r) {
            qb[(cr0 + r) * 302 + n] = f2b(c0[r]);
            qb[(cr0 + 16 + r) * 302 + n] = f2b(c1[r]);
          }
        } else if (n < 306) {
          float* aMh = miscf + (n - 300) * 64;
#pragma unroll
          for (int r = 0; r < 4; ++r) {
            aMh[cr0 + r] = c0[r] * scale;
            aMh[cr0 + 16 + r] = c1[r] * scale;
          }
        }
      } else if (j < 39) {
        int n = (j - 20) * 16 + l15;
        if (n < 300) {
#pragma unroll
          for (int r = 0; r < 4; ++r) {
            kb[(cr0 + r) * 306 + n] = f2b(c0[r]);
            kb[(cr0 + 16 + r) * 306 + n] = f2b(c1[r]);
          }
        }
      } else {
        int n = (j - 39) * 16 + l15;
        if (n < 300) {
#pragma unroll
          for (int r = 0; r < 4; ++r) {
            vb[(cr0 + r) * 302 + n] = f2b(c0[r]);
            vb[(cr0 + 16 + r) * 302 + n] = f2b(c1[r]);
          }
        }
      }
    };
    short8 wb0[10], wb1[10];
    loadBT<10>(wb0, jobPtr(w4));
    f32x4 c0, c1;
    int j = w4;
    while (true) {
      if (j + 4 < 58) loadBT<10>(wb1, jobPtr(j + 4));
      chain2<10>(ax0, ax1, wb0, c0, c1);
      bEpi(j, c0, c1);
      j += 4; if (j >= 58) break;
      if (j + 4 < 58) loadBT<10>(wb0, jobPtr(j + 4));
      chain2<10>(ax0, ax1, wb1, c0, c1);
      bEpi(j, c0, c1);
      j += 4; if (j >= 58) break;
    }
  }
  __syncthreads();   // B1

  // ---- Stage C: wave h handles head h entirely in-wave ----
  if (wv < 6) {
    const int h = wv;
    float* aMh = miscf + h * 64;
    // alpha = softmax(logits)
    float lgt = aMh[lane];
    float m = lgt;
#pragma unroll
    for (int off = 32; off; off >>= 1) m = fmaxf(m, __shfl_xor(m, off));
    float e = __expf(lgt - m);
    float ss = e;
#pragma unroll
    for (int off = 32; off; off >>= 1) ss += __shfl_xor(ss, off);
    aMh[lane] = e / ss;
    // g[d] = sum_s alpha[s] q[s,d]
    float g = 0.f;
    if (lane < 50) {
      const unsigned short* qcol = qb + 50 * h + lane;
      for (int s = 0; s < 64; ++s) g += aMh[s] * b2f(qcol[s * 302]);
    }
    float gw = (lane < 50) ? g * wk_attn[h * 50 + lane] : 0.f;
    aMh[lane] = gw;
    // beta logits p[s] = sum_d gw[d] k[s,d]
    float p = 0.f;
    {
      const unsigned short* krow = kb + lane * 306 + 50 * h;
      for (int d = 0; d < 50; ++d) p += aMh[d] * b2f(krow[d]);
    }
    p *= scale;
    m = p;
#pragma unroll
    for (int off = 32; off; off >>= 1) m = fmaxf(m, __shfl_xor(m, off));
    e = __expf(p - m);
    ss = e;
#pragma unroll
    for (int off = 32; off; off >>= 1) ss += __shfl_xor(ss, off);
    aMh[lane] = e / ss;   // beta
    // gk[d] = g[d] * sum_s beta[s] k[s,d]
    if (lane < 50) {
      float gks = 0.f;
      const unsigned short* kcol = kb + 50 * h + lane;
      for (int s = 0; s < 64; ++s) gks += aMh[s] * b2f(kcol[s * 306]);
      gkf[50 * h + lane] = g * gks;
    }
  }
  __syncthreads();   // B2

  // ---- attn_out = q@Wo + (gk o v)@Wro + bob -> kb ----
  {
    short8 aq0[10], aq1[10];
#pragma unroll
    for (int kt = 0; kt < 10; ++kt) {
      aq0[kt] = *(const short8*)&qb[arow0 * 302 + kt * 32 + kofs];
      aq1[kt] = *(const short8*)&qb[arow1 * 302 + kt * 32 + kofs];
    }
    gemm2<10>(ws + OF, aq0, aq1, w4, 19, lane, [&](int t, f32x4 c0, f32x4 c1) {
      int n = t * 16 + l15;
      float bias = bobf[n];
#pragma unroll
      for (int r = 0; r < 4; ++r) {
        kb[(cr0 + r) * 306 + n] = (n < 300) ? f2b(c0[r] + bias) : (unsigned short)0;
        kb[(cr0 + 16 + r) * 306 + n] = (n < 300) ? f2b(c1[r] + bias) : (unsigned short)0;
      }
    });
    // u fragments (gk o v), guarded at kt=9 against over-read garbage
    short8 au0[10], au1[10];
#pragma unroll
    for (int kt = 0; kt < 10; ++kt) {
      short8 vf0 = *(const short8*)&vb[arow0 * 302 + kt * 32 + kofs];
      short8 vf1 = *(const short8*)&vb[arow1 * 302 + kt * 32 + kofs];
      f32x4 g0 = *(const f32x4*)&gkf[kt * 32 + kofs];
      f32x4 g1 = *(const f32x4*)&gkf[kt * 32 + kofs + 4];
      short8 u0, u1;
#pragma unroll
      for (int j = 0; j < 8; ++j) {
        float gv = (j < 4) ? g0[j] : g1[j - 4];
        if (kt == 9 && (288 + kofs + j) >= 300) { u0[j] = 0; u1[j] = 0; }
        else {
          u0[j] = (short)f2b(gv * b2f((unsigned short)vf0[j]));
          u1[j] = (short)f2b(gv * b2f((unsigned short)vf1[j]));
        }
      }
      au0[kt] = u0; au1[kt] = u1;
    }
    gemm2<10>(ws + RF, au0, au1, w4, 19, lane, [&](int t, f32x4 c0, f32x4 c1) {
      int n = t * 16 + l15;
      if (n < 300) {
#pragma unroll
        for (int r = 0; r < 4; ++r) {
          int i0 = (cr0 + r) * 306 + n, i1 = (cr0 + 16 + r) * 306 + n;
          kb[i0] = f2b(b2f(kb[i0]) + c0[r]);
          kb[i1] = f2b(b2f(kb[i1]) + c1[r]);
        }
      }
    });
  }
  __syncthreads();   // B3

  // ---- h = attn_out @ Wp + bp -> hb [64][402] (overlays qb+vb) ----
  {
    for (int i = tid; i < 128; i += 512) hb[(i >> 1) * 402 + 400 + (i & 1)] = 0;
    short8 ao0[10], ao1[10];
#pragma unroll
    for (int kt = 0; kt < 10; ++kt) {
      ao0[kt] = *(const short8*)&kb[arow0 * 306 + kt * 32 + kofs];
      ao1[kt] = *(const short8*)&kb[arow1 * 306 + kt * 32 + kofs];
    }
    gemm2<10>(ws + PFW, ao0, ao1, w4, 25, lane, [&](int t, f32x4 c0, f32x4 c1) {
      int n = t * 16 + l15;
      float bias = bp_[n];
#pragma unroll
      for (int r = 0; r < 4; ++r) {
        hb[(cr0 + r) * 402 + n] = f2b(c0[r] + bias);
        hb[(cr0 + 16 + r) * 402 + n] = f2b(c1[r] + bias);
      }
    });
  }
  __syncthreads();   // B4

  // ---- scores = tanh(h@Wa + ba) @ va ----
  {
    short8 ah0[13], ah1[13];
#pragma unroll
    for (int kt = 0; kt < 13; ++kt) {
      ah0[kt] = *(const short8*)&hb[arow0 * 402 + kt * 32 + kofs];
      ah1[kt] = *(const short8*)&hb[arow1 * 402 + kt * 32 + kofs];
    }
    float sp0[4] = {0.f, 0.f, 0.f, 0.f}, sp1[4] = {0.f, 0.f, 0.f, 0.f};
    for (int t = w4; t < 13; t += 4) {
      short8 bfa[13];
      loadBT<13>(bfa, ws + AFW + (size_t)t * 6656 + lane * 8);
      f32x4 c0, c1;
      chain2<13>(ah0, ah1, bfa, c0, c1);
      int n = t * 16 + l15;
      if (n < 200) {
        float ban = ba_[n], van = va_[n];
#pragma unroll
        for (int r = 0; r < 4; ++r) {
          sp0[r] += tanhf(c0[r] + ban) * van;
          sp1[r] += tanhf(c1[r] + ban) * van;
        }
      }
    }
#pragma unroll
    for (int off = 1; off < 16; off <<= 1) {
#pragma unroll
      for (int r = 0; r < 4; ++r) {
        sp0[r] += __shfl_xor(sp0[r], off);
        sp1[r] += __shfl_xor(sp1[r], off);
      }
    }
    if (l15 == 0) {
#pragma unroll
      for (int r = 0; r < 4; ++r) {
        scp[w4 * 64 + cr0 + r] = sp0[r];
        scp[w4 * 64 + cr0 + 16 + r] = sp1[r];
      }
    }
  }
  __syncthreads();   // B5
  if (wv == 0) {
    float x = scp[lane] + scp[64 + lane] + scp[128 + lane] + scp[192 + lane];
    float m = x;
#pragma unroll
    for (int off = 32; off; off >>= 1) m = fmaxf(m, __shfl_xor(m, off));
    float e = __expf(x - m);
    float ss = e;
#pragma unroll
    for (int off = 32; off; off >>= 1) ss += __shfl_xor(ss, off);
    wsm[lane] = e / ss;
  }
  __syncthreads();   // B6

  // ---- pooled[e] = sum_s wsm[s] h[s][e] ----
  if (tid < 400) {
    float a0 = 0.f, a1 = 0.f, a2 = 0.f, a3 = 0.f;
    for (int s = 0; s < 64; s += 4) {
      a0 += wsm[s] * b2f(hb[s * 402 + tid]);
      a1 += wsm[s + 1] * b2f(hb[(s + 1) * 402 + tid]);
      a2 += wsm[s + 2] * b2f(hb[(s + 2) * 402 + tid]);
      a3 += wsm[s + 3] * b2f(hb[(s + 3) * 402 + tid]);
    }
    out[(size_t)b * 400 + tid] = (a0 + a1) + (a2 + a3);
  }
}

extern "C" void kernel_launch(void* const* d_in, const int* in_sizes, int n_in,
                              void* d_out, int out_size, void* d_ws, size_t ws_size,
                              hipStream_t stream) {
  (void)in_sizes; (void)n_in; (void)out_size; (void)ws_size;
  const int* tokens = (const int*)d_in[0];
  const float* emb = (const float*)d_in[1];
  const float* Wq = (const float*)d_in[2];
  const float* Wk = (const float*)d_in[3];
  const float* Wv = (const float*)d_in[4];
  const float* wq_attn = (const float*)d_in[5];
  const float* wk_attn = (const float*)d_in[6];
  const float* Wr = (const float*)d_in[7];
  const float* br = (const float*)d_in[8];
  const float* Wo = (const float*)d_in[9];
  const float* bo = (const float*)d_in[10];
  const float* Wp = (const float*)d_in[11];
  const float* bp = (const float*)d_in[12];
  const float* Wa = (const float*)d_in[13];
  const float* ba = (const float*)d_in[14];
  const float* va = (const float*)d_in[15];
  unsigned short* wsb = (unsigned short*)d_ws;
  float* out = (float*)d_out;

  prep_weights<<<(PREP_TOTAL + 255) / 256, 256, 0, stream>>>(Wq, Wk, Wv, Wr, Wo, Wp, Wa,
                                                             wq_attn, br, bo, wsb);
  doc_encoder<<<4096, 512, 0, stream>>>(tokens, emb, wk_attn, bp, ba, va, wsb, out);
}